// Round 5
// baseline (308.335 us; speedup 1.0000x reference)
//
#include <hip/hip_runtime.h>
#include <stdint.h>

// Problem constants (match reference)
#define B_TOT 4096
#define T_LEN 2048
#define D_IN  10
#define OUT_N 30
#define TT    64                       // timesteps per LDS tile
#define NT    (T_LEN/TT)               // 32 tiles
#define SMP_BLK 8                      // samples per block (2 per wave, lanes 0-31)
#define TILE_FLOATS (TT*SMP_BLK*D_IN)  // 5120 floats = 20 KB per buffer
#define NLD   (TILE_FLOATS/(4*64))     // global_load_lds per wave per tile = 20

// async global->LDS, width 4 (per-lane arbitrary global addr, linear LDS dest)
#define GLD4(gptr, lptr) __builtin_amdgcn_global_load_lds( \
    (const __attribute__((address_space(1))) void*)(gptr),  \
    (__attribute__((address_space(3))) void*)(lptr), 4, 0, 0)

// DPP cross-lane move (VALU pipe). quad_perm broadcast k: ctrl=k*0x55.
// row_ror:N: ctrl=0x120+N -> dest lane i receives src lane (i-N) mod 16.
template<int CTRL>
__device__ __forceinline__ float dppf(float x) {
    return __int_as_float(
        __builtin_amdgcn_mov_dpp(__float_as_int(x), CTRL, 0xF, 0xF, true));
}

// raw v_exp_f32 (2^x)
__device__ __forceinline__ float fast_exp2(float x) {
#if __has_builtin(__builtin_amdgcn_exp2f)
    return __builtin_amdgcn_exp2f(x);
#else
    float r; asm("v_exp_f32 %0, %1" : "=v"(r) : "v"(x)); return r;
#endif
}

// Main LSTM scan. 16 lanes per sample; 2 samples per wave (lanes 0-31);
// lanes 32-63 mirror the same two samples (harmless duplicate compute) so
// no divergence. 2 blocks/CU -> 2 waves/SIMD to hide chain-latency stalls.
// lane layout in a 16-lane group (one DPP row): unit u=(lane>>2)&3,
// gate type tau=lane&3. Weight row (PyTorch i,f,g,o): r = tau*4+u.
// State pre-scaled: cs = -2log2(e)*c, so tanh(c)=2*rcp(1+exp2(cs))-1.
__launch_bounds__(256, 2)
__global__ void lstm_scan_kernel(const float* __restrict__ X,
                                 const float* __restrict__ W_ih,
                                 const float* __restrict__ W_hh,
                                 const float* __restrict__ b_ih,
                                 const float* __restrict__ b_hh,
                                 float* __restrict__ hT)
{
    __shared__ float lds[2][TILE_FLOATS];

    const int tid  = threadIdx.x;
    const int lane = tid & 63;
    const int w    = tid >> 6;              // wave within block (0..3)
    const int gl   = (lane & 31) >> 4;      // sample within wave (0..1), mirrored
    const int g    = w * 2 + gl;            // sample within block (0..7)
    const int u    = (tid >> 2) & 3;        // hidden unit
    const int tau  = tid & 3;               // 0=i,1=f,2=g,3=o
    const int r    = tau * 4 + u;           // weight row

    const float KT = -2.8853900817779268f;   // -2*log2(e)
    const float KS = -1.4426950408889634f;   // -log2(e)
    // pre-activation accumulated PRE-SCALED by mneg; a = fma(k1, rcp(1+exp2(acc)), k0)
    //   tau=0 (i): a = KT*sigmoid   tau=1 (f): a = sigmoid
    //   tau=2 (g): a = tanh         tau=3 (o): a = 2*sigmoid
    const float mneg = (tau == 2) ? KT : KS;
    const float k1   = (tau == 0) ? KT : ((tau == 1) ? 1.0f : 2.0f);
    const float k0   = (tau == 2) ? -1.0f : 0.0f;

    // per-lane constant weights, pre-scaled by mneg (VGPR-resident)
    float wih[10];
    #pragma unroll
    for (int d0 = 0; d0 < 10; ++d0) wih[d0] = W_ih[r*10 + d0] * mneg;
    // rotated W_hh columns to match row_ror data placement
    const float whhA = W_hh[r*4 +  u        ] * mneg;
    const float whhB = W_hh[r*4 + ((u+3)&3)] * mneg;
    const float whhC = W_hh[r*4 + ((u+2)&3)] * mneg;
    const float whhD = W_hh[r*4 + ((u+1)&3)] * mneg;
    const float bsum = (b_ih[r] + b_hh[r]) * mneg;

    // staging offsets: LDS float index p = (t*SMP_BLK + s)*10 + d
    uint32_t voff[NLD];
    const uint32_t samp0 = (uint32_t)blockIdx.x * SMP_BLK;
    #pragma unroll
    for (int kk = 0; kk < NLD; ++kk) {
        int p   = (w*NLD + kk)*64 + lane;
        int t   = p / 80;               // D_IN*SMP_BLK = 80
        int rem = p - t*80;
        int s   = rem / 10;
        int d0  = rem - s*10;
        voff[kk] = (samp0 + (uint32_t)s) * (uint32_t)(T_LEN*D_IN*4)
                 + (uint32_t)(t*40 + d0*4);
    }
    const char* Xc = (const char*)X;

    // prologue: stage tile 0 into buf 0
    #pragma unroll
    for (int kk = 0; kk < NLD; ++kk)
        GLD4(Xc + voff[kk], &lds[0][(w*NLD+kk)*64]);
    __syncthreads();

    float cs = 0.f, hown = 0.f;

    for (int tile = 0; tile < NT; ++tile) {
        const int cur = tile & 1;
        if (tile + 1 < NT) {
            const uint32_t add = (uint32_t)(tile+1) * (uint32_t)(TT*D_IN*4);
            #pragma unroll
            for (int kk = 0; kk < NLD; ++kk)
                GLD4(Xc + (voff[kk] + add), &lds[cur^1][(w*NLD+kk)*64]);
        }
        // broadcast reads: all 16 lanes of group g read the same 40B row.
        // step stride = SMP_BLK*40B = 320B = 40 float2.
        const float2* xp = (const float2*)((const char*)&lds[cur][0] + g*40);

        // pipeline preload: xacc(0) and x(1) regs
        float2 xB[5];
        #pragma unroll
        for (int k = 0; k < 5; ++k) xB[k] = xp[40 + k];
        float xaccA;
        {
            float2 x0 = xp[0], x1 = xp[1], x2 = xp[2], x3 = xp[3], x4 = xp[4];
            float acc = bsum;
            acc = fmaf(wih[0], x0.x, acc); acc = fmaf(wih[1], x0.y, acc);
            acc = fmaf(wih[2], x1.x, acc); acc = fmaf(wih[3], x1.y, acc);
            acc = fmaf(wih[4], x2.x, acc); acc = fmaf(wih[5], x2.y, acc);
            acc = fmaf(wih[6], x3.x, acc); acc = fmaf(wih[7], x3.y, acc);
            acc = fmaf(wih[8], x4.x, acc); acc = fmaf(wih[9], x4.y, acc);
            xaccA = acc;
        }

        #pragma unroll
        for (int t = 0; t < TT; ++t) {
            // issue loads for x(t+2) — consumed one full iteration later
            float2 xN[5];
            if (t + 2 < TT) {
                #pragma unroll
                for (int k = 0; k < 5; ++k) xN[k] = xp[(t+2)*40 + k];
            }
            // x-projection for step t+1 (independent: fills chain stalls)
            float xaccB = 0.f;
            if (t + 1 < TT) {
                float acc = bsum;
                acc = fmaf(wih[0], xB[0].x, acc); acc = fmaf(wih[1], xB[0].y, acc);
                acc = fmaf(wih[2], xB[1].x, acc); acc = fmaf(wih[3], xB[1].y, acc);
                acc = fmaf(wih[4], xB[2].x, acc); acc = fmaf(wih[5], xB[2].y, acc);
                acc = fmaf(wih[6], xB[3].x, acc); acc = fmaf(wih[7], xB[3].y, acc);
                acc = fmaf(wih[8], xB[4].x, acc); acc = fmaf(wih[9], xB[4].y, acc);
                xaccB = acc;
            }
            // ---- serial chain for step t ----
            float hB = dppf<0x124>(hown);   // h[(u-1)&3]
            float hC = dppf<0x128>(hown);   // h[(u-2)&3]
            float hD = dppf<0x12C>(hown);   // h[(u+1)&3]
            float u1 = fmaf(whhA, hown, xaccA);
            float acc = fmaf(whhB, hB, u1) + fmaf(whhD, hD, whhC * hC);
            float e  = fast_exp2(acc);
            float a  = fmaf(k1, __builtin_amdgcn_rcpf(1.0f + e), k0);
            float gi = dppf<0x00>(a);       // KT*sigmoid(i)
            float gf = dppf<0x55>(a);       // sigmoid(f)
            float gg = dppf<0xAA>(a);       // tanh(g)
            float go = dppf<0xFF>(a);       // 2*sigmoid(o)
            float mgo = -0.5f * go;         // off-chain
            cs = fmaf(gf, cs, gi * gg);     // cs = KT * c
            float e2 = fast_exp2(cs);
            float r2 = __builtin_amdgcn_rcpf(1.0f + e2);
            hown = fmaf(go, r2, mgo);       // = sigmoid(o)*tanh(c)
            // rotate pipeline
            #pragma unroll
            for (int k = 0; k < 5; ++k) xB[k] = xN[k];
            xaccA = xaccB;
        }
        __syncthreads();  // drains next-tile prefetch + protects buffer swap
    }

    if (tau == 0 && lane < 32) hT[(samp0 + g)*4 + u] = hown;
}

// Head: logits = hT @ W_out^T + b_out, then softmax. One thread per sample.
__global__ void head_kernel(const float* __restrict__ hT,
                            const float* __restrict__ W_out,
                            const float* __restrict__ b_out,
                            float* __restrict__ out)
{
    int b = blockIdx.x * blockDim.x + threadIdx.x;
    if (b >= B_TOT) return;
    float4 h = ((const float4*)hT)[b];
    float lg[OUT_N];
    float m = -1e30f;
    #pragma unroll
    for (int o = 0; o < OUT_N; ++o) {
        float v = b_out[o];
        v = fmaf(W_out[o*4+0], h.x, v);
        v = fmaf(W_out[o*4+1], h.y, v);
        v = fmaf(W_out[o*4+2], h.z, v);
        v = fmaf(W_out[o*4+3], h.w, v);
        lg[o] = v;
        m = fmaxf(m, v);
    }
    float s = 0.f;
    #pragma unroll
    for (int o = 0; o < OUT_N; ++o) {
        float e = fast_exp2((lg[o] - m) * 1.4426950408889634f);
        lg[o] = e;
        s += e;
    }
    float rs = 1.0f / s;
    #pragma unroll
    for (int o = 0; o < OUT_N; ++o) out[(size_t)b*OUT_N + o] = lg[o] * rs;
}

extern "C" void kernel_launch(void* const* d_in, const int* in_sizes, int n_in,
                              void* d_out, int out_size, void* d_ws, size_t ws_size,
                              hipStream_t stream)
{
    const float* X     = (const float*)d_in[0];
    const float* W_ih  = (const float*)d_in[1];
    const float* W_hh  = (const float*)d_in[2];
    const float* b_ih  = (const float*)d_in[3];
    const float* b_hh  = (const float*)d_in[4];
    const float* W_out = (const float*)d_in[5];
    const float* b_out = (const float*)d_in[6];
    float* out = (float*)d_out;
    float* hTs = (float*)d_ws;   // 4096*4 floats = 64 KB scratch

    lstm_scan_kernel<<<B_TOT/SMP_BLK, 256, 0, stream>>>(X, W_ih, W_hh, b_ih, b_hh, hTs);
    head_kernel<<<B_TOT/256, 256, 0, stream>>>(hTs, W_out, b_out, out);
}

// Round 7
// 252.200 us; speedup vs baseline: 1.2226x; 1.2226x over previous
//
#include <hip/hip_runtime.h>
#include <stdint.h>

// Problem constants (match reference)
#define B_TOT 4096
#define T_LEN 2048
#define D_IN  10
#define OUT_N 30
#define CSTEP 32                        // timesteps per chunk
#define NCH   (T_LEN/CSTEP)             // 64 chunks
#define SMP_BLK 16                      // samples per block
#define XBUF_F (CSTEP*SMP_BLK*D_IN)     // 5120 floats = 20 KB per X buffer
#define ABUF_F (CSTEP*SMP_BLK*16)       // 8192 floats = 32 KB per xacc buffer
#define NLD   (XBUF_F/(4*64))           // width-4 loads per producer wave = 20
#define CH_BYTES (CSTEP*D_IN*4)         // global X advance per chunk = 1280 B

// async global->LDS, width 4 (per-lane arbitrary global addr, linear LDS dest)
#define GLD4(gptr, lptr) __builtin_amdgcn_global_load_lds( \
    (const __attribute__((address_space(1))) void*)(gptr),  \
    (__attribute__((address_space(3))) void*)(lptr), 4, 0, 0)

// DPP cross-lane move (VALU pipe). quad_perm broadcast k: ctrl=k*0x55.
// row_ror:N: ctrl=0x120+N -> dest lane i receives src lane (i-N) mod 16.
template<int CTRL>
__device__ __forceinline__ float dppf(float x) {
    return __int_as_float(
        __builtin_amdgcn_mov_dpp(__float_as_int(x), CTRL, 0xF, 0xF, true));
}

// raw v_exp_f32 (2^x)
__device__ __forceinline__ float fast_exp2(float x) {
#if __has_builtin(__builtin_amdgcn_exp2f)
    return __builtin_amdgcn_exp2f(x);
#else
    float r; asm("v_exp_f32 %0, %1" : "=v"(r) : "v"(x)); return r;
#endif
}

// Producer/consumer LSTM scan.
// Block = 512 threads = 8 waves: waves 0-3 consumers (4 samples each, 16
// lanes/sample), waves 4-7 producers (compute xacc = mneg*(W_ih x + b) for
// the matching 4 samples, one chunk ahead, into double-buffered LDS).
// 256 blocks -> 1 block/CU, 2 waves/SIMD with DISJOINT work.
// Within a 16-lane group (one DPP row): u=(lr>>2)&3, tau=lr&3, weight row
// rw = tau*4+u (PyTorch i,f,g,o). Position within xacc row is lr (not rw):
// producer lane lr computes row rw(lr) and stores at +lr; consumer lane lr
// reads +lr and uses the same rw(lr) for its W_hh row. State pre-scaled:
// cs = -2log2(e)*c, so tanh(c)=2*rcp(1+exp2(cs))-1.
__launch_bounds__(512, 2)
__global__ void lstm_scan_kernel(const float* __restrict__ X,
                                 const float* __restrict__ W_ih,
                                 const float* __restrict__ W_hh,
                                 const float* __restrict__ b_ih,
                                 const float* __restrict__ b_hh,
                                 float* __restrict__ hT)
{
    __shared__ float xbuf[2][XBUF_F];   // 40 KB: X chunks [t][s][10]
    __shared__ float abuf[2][ABUF_F];   // 64 KB: xacc chunks [t][s][16]

    const int tid  = threadIdx.x;
    const int lane = tid & 63;
    const int w    = tid >> 6;          // wave in block (0..7)
    const int lr   = lane & 15;         // position within 16-lane group
    const int grp  = lane >> 4;         // sample within wave (0..3)
    const int u    = (lr >> 2) & 3;     // hidden unit
    const int tau  = lr & 3;            // 0=i,1=f,2=g,3=o
    const int rw   = tau * 4 + u;       // weight row
    const uint32_t samp0 = (uint32_t)blockIdx.x * SMP_BLK;

    const float KT = -2.8853900817779268f;   // -2*log2(e)
    const float KS = -1.4426950408889634f;   // -log2(e)
    const float mneg = (tau == 2) ? KT : KS;

    if (w >= 4) {
        // ---------------- PRODUCER ----------------
        const int pw = w - 4;
        const int sg = pw * 4 + grp;    // sample within block (0..15)
        float wih[10];
        #pragma unroll
        for (int d0 = 0; d0 < 10; ++d0) wih[d0] = W_ih[rw*10 + d0] * mneg;
        const float bsum = (b_ih[rw] + b_hh[rw]) * mneg;

        // staging offsets: element p = [t][s][d] within a chunk
        uint32_t voff[NLD];
        #pragma unroll
        for (int kk = 0; kk < NLD; ++kk) {
            int p   = (pw*NLD + kk)*64 + lane;
            int t   = p / 160;          // D_IN*SMP_BLK = 160
            int rem = p - t*160;
            int s   = rem / 10;
            int d0  = rem - s*10;
            voff[kk] = (samp0 + (uint32_t)s) * (uint32_t)(T_LEN*D_IN*4)
                     + (uint32_t)(t*40 + d0*4);
        }
        const char* Xc = (const char*)X;

        // xproj of one chunk from xbuf[bb] -> abuf[bb]
        auto produce = [&](int bb) {
            #pragma unroll 4
            for (int t = 0; t < CSTEP; ++t) {
                const float2* xp =
                    (const float2*)&xbuf[bb][(t*SMP_BLK + sg)*10];
                float2 x0 = xp[0], x1 = xp[1], x2 = xp[2],
                       x3 = xp[3], x4 = xp[4];
                float acc = bsum;
                acc = fmaf(wih[0], x0.x, acc); acc = fmaf(wih[1], x0.y, acc);
                acc = fmaf(wih[2], x1.x, acc); acc = fmaf(wih[3], x1.y, acc);
                acc = fmaf(wih[4], x2.x, acc); acc = fmaf(wih[5], x2.y, acc);
                acc = fmaf(wih[6], x3.x, acc); acc = fmaf(wih[7], x3.y, acc);
                acc = fmaf(wih[8], x4.x, acc); acc = fmaf(wih[9], x4.y, acc);
                abuf[bb][(t*SMP_BLK + sg)*16 + lr] = acc;
            }
        };

        // prologue: stage X(0)
        #pragma unroll
        for (int kk = 0; kk < NLD; ++kk)
            GLD4(Xc + voff[kk], &xbuf[0][(pw*NLD+kk)*64]);
        __syncthreads();                               // (1) X0 ready
        // stage X(1) (flies during compute), compute xacc(0)
        #pragma unroll
        for (int kk = 0; kk < NLD; ++kk)
            GLD4(Xc + (voff[kk] + CH_BYTES), &xbuf[1][(pw*NLD+kk)*64]);
        produce(0);
        __syncthreads();                               // (2) A0 + X1 ready

        for (int k = 0; k < NCH; ++k) {
            if (k + 1 < NCH) {
                if (k + 2 < NCH) {
                    const uint32_t add = (uint32_t)(k+2) * CH_BYTES;
                    #pragma unroll
                    for (int kk = 0; kk < NLD; ++kk)
                        GLD4(Xc + (voff[kk] + add),
                             &xbuf[k&1][(pw*NLD+kk)*64]);
                }
                produce((k+1)&1);
            }
            __syncthreads();
        }
    } else {
        // ---------------- CONSUMER ----------------
        const int sg = w * 4 + grp;     // sample within block (0..15)
        //   tau=0 (i): a = KT*sigmoid   tau=1 (f): a = sigmoid
        //   tau=2 (g): a = tanh         tau=3 (o): a = 2*sigmoid
        const float k1 = (tau == 0) ? KT : ((tau == 1) ? 1.0f : 2.0f);
        const float k0 = (tau == 2) ? -1.0f : 0.0f;
        // rotated W_hh columns to match row_ror data placement
        const float whhA = W_hh[rw*4 +  u        ] * mneg;
        const float whhB = W_hh[rw*4 + ((u+3)&3)] * mneg;
        const float whhC = W_hh[rw*4 + ((u+2)&3)] * mneg;
        const float whhD = W_hh[rw*4 + ((u+1)&3)] * mneg;

        __syncthreads();                               // (1)
        __syncthreads();                               // (2)

        float cs = 0.f, hown = 0.f;
        for (int k = 0; k < NCH; ++k) {
            const float* ab = &abuf[k&1][sg*16 + lr];  // step stride 256 floats
            float xr0 = ab[0];
            float xr1 = ab[256];
            #pragma unroll
            for (int t = 0; t < CSTEP; ++t) {
                float xr2 = 0.f;
                if (t + 2 < CSTEP) xr2 = ab[(t+2)*256];
                // ---- serial chain for step t ----
                float hB = dppf<0x124>(hown);   // h[(u-1)&3]
                float hC = dppf<0x128>(hown);   // h[(u-2)&3]
                float hD = dppf<0x12C>(hown);   // h[(u+1)&3]
                float u1 = fmaf(whhA, hown, xr0);
                float acc = fmaf(whhB, hB, u1) + fmaf(whhD, hD, whhC * hC);
                float e  = fast_exp2(acc);
                float a  = fmaf(k1, __builtin_amdgcn_rcpf(1.0f + e), k0);
                float gi = dppf<0x00>(a);       // KT*sigmoid(i)
                float gf = dppf<0x55>(a);       // sigmoid(f)
                float gg = dppf<0xAA>(a);       // tanh(g)
                float go = dppf<0xFF>(a);       // 2*sigmoid(o)
                float mgo = -0.5f * go;         // off-chain
                cs = fmaf(gf, cs, gi * gg);     // cs = KT * c
                float e2 = fast_exp2(cs);
                float r2 = __builtin_amdgcn_rcpf(1.0f + e2);
                hown = fmaf(go, r2, mgo);       // = sigmoid(o)*tanh(c)
                xr0 = xr1; xr1 = xr2;
            }
            __syncthreads();
        }
        if (tau == 0) hT[(samp0 + sg)*4 + u] = hown;
    }
}

// Head: logits = hT @ W_out^T + b_out, then softmax. One thread per sample.
__global__ void head_kernel(const float* __restrict__ hT,
                            const float* __restrict__ W_out,
                            const float* __restrict__ b_out,
                            float* __restrict__ out)
{
    int b = blockIdx.x * blockDim.x + threadIdx.x;
    if (b >= B_TOT) return;
    float4 h = ((const float4*)hT)[b];
    float lg[OUT_N];
    float m = -1e30f;
    #pragma unroll
    for (int o = 0; o < OUT_N; ++o) {
        float v = b_out[o];
        v = fmaf(W_out[o*4+0], h.x, v);
        v = fmaf(W_out[o*4+1], h.y, v);
        v = fmaf(W_out[o*4+2], h.z, v);
        v = fmaf(W_out[o*4+3], h.w, v);
        lg[o] = v;
        m = fmaxf(m, v);
    }
    float s = 0.f;
    #pragma unroll
    for (int o = 0; o < OUT_N; ++o) {
        float e = fast_exp2((lg[o] - m) * 1.4426950408889634f);
        lg[o] = e;
        s += e;
    }
    float rs = 1.0f / s;
    #pragma unroll
    for (int o = 0; o < OUT_N; ++o) out[(size_t)b*OUT_N + o] = lg[o] * rs;
}

extern "C" void kernel_launch(void* const* d_in, const int* in_sizes, int n_in,
                              void* d_out, int out_size, void* d_ws, size_t ws_size,
                              hipStream_t stream)
{
    const float* X     = (const float*)d_in[0];
    const float* W_ih  = (const float*)d_in[1];
    const float* W_hh  = (const float*)d_in[2];
    const float* b_ih  = (const float*)d_in[3];
    const float* b_hh  = (const float*)d_in[4];
    const float* W_out = (const float*)d_in[5];
    const float* b_out = (const float*)d_in[6];
    float* out = (float*)d_out;
    float* hTs = (float*)d_ws;   // 4096*4 floats = 64 KB scratch

    lstm_scan_kernel<<<B_TOT/SMP_BLK, 512, 0, stream>>>(X, W_ih, W_hh, b_ih, b_hh, hTs);
    head_kernel<<<B_TOT/256, 256, 0, stream>>>(hTs, W_out, b_out, out);
}

// Round 8
// 251.296 us; speedup vs baseline: 1.2270x; 1.0036x over previous
//
#include <hip/hip_runtime.h>
#include <stdint.h>

// Problem constants (match reference)
#define B_TOT 4096
#define T_LEN 2048
#define D_IN  10
#define OUT_N 30
#define CSTEP 32                        // timesteps per chunk
#define NCH   (T_LEN/CSTEP)             // 64 chunks
#define SMP_BLK 16                      // samples per block
#define XBUF_F (CSTEP*SMP_BLK*D_IN)     // 5120 floats = 20 KB per X buffer
#define ABUF_F (CSTEP*SMP_BLK*16)       // 8192 floats = 32 KB per xacc buffer
#define NLD   (XBUF_F/(4*64))           // width-4 loads per producer wave = 20
#define CH_BYTES (CSTEP*D_IN*4)         // global X advance per chunk = 1280 B

// async global->LDS, width 4 (per-lane arbitrary global addr, linear LDS dest)
#define GLD4(gptr, lptr) __builtin_amdgcn_global_load_lds( \
    (const __attribute__((address_space(1))) void*)(gptr),  \
    (__attribute__((address_space(3))) void*)(lptr), 4, 0, 0)

// DPP cross-lane move (VALU pipe). quad_perm broadcast k: ctrl=k*0x55.
// row_ror:N: ctrl=0x120+N -> dest lane i receives src lane (i-N) mod 16.
template<int CTRL>
__device__ __forceinline__ float dppf(float x) {
    return __int_as_float(
        __builtin_amdgcn_mov_dpp(__float_as_int(x), CTRL, 0xF, 0xF, true));
}

// raw v_exp_f32 (2^x)
__device__ __forceinline__ float fast_exp2(float x) {
#if __has_builtin(__builtin_amdgcn_exp2f)
    return __builtin_amdgcn_exp2f(x);
#else
    float r; asm("v_exp_f32 %0, %1" : "=v"(r) : "v"(x)); return r;
#endif
}

// Producer/consumer LSTM scan.
// Block = 512 threads = 8 waves: waves 0-3 consumers (4 samples each, 16
// lanes/sample), waves 4-7 producers (compute xacc = mneg*(W_ih x + b) for
// the matching 4 samples, one chunk ahead, into double-buffered LDS).
// 256 blocks -> 1 block/CU, 2 waves/SIMD with DISJOINT work.
// R8 change: consumer preloads the whole chunk's xacc into 32 registers at
// the chunk boundary -> ZERO memory ops inside the 32-step serial loop
// (tests: was per-step lgkmcnt wait sitting on the dependency chain?).
// Within a 16-lane group (one DPP row): u=(lr>>2)&3, tau=lr&3, weight row
// rw = tau*4+u (PyTorch i,f,g,o). State pre-scaled: cs = -2log2(e)*c, so
// tanh(c)=2*rcp(1+exp2(cs))-1.
__launch_bounds__(512, 2)
__global__ void lstm_scan_kernel(const float* __restrict__ X,
                                 const float* __restrict__ W_ih,
                                 const float* __restrict__ W_hh,
                                 const float* __restrict__ b_ih,
                                 const float* __restrict__ b_hh,
                                 float* __restrict__ hT)
{
    __shared__ float xbuf[2][XBUF_F];   // 40 KB: X chunks [t][s][10]
    __shared__ float abuf[2][ABUF_F];   // 64 KB: xacc chunks [t][s][16]

    const int tid  = threadIdx.x;
    const int lane = tid & 63;
    const int w    = tid >> 6;          // wave in block (0..7)
    const int lr   = lane & 15;         // position within 16-lane group
    const int grp  = lane >> 4;         // sample within wave (0..3)
    const int u    = (lr >> 2) & 3;     // hidden unit
    const int tau  = lr & 3;            // 0=i,1=f,2=g,3=o
    const int rw   = tau * 4 + u;       // weight row
    const uint32_t samp0 = (uint32_t)blockIdx.x * SMP_BLK;

    const float KT = -2.8853900817779268f;   // -2*log2(e)
    const float KS = -1.4426950408889634f;   // -log2(e)
    const float mneg = (tau == 2) ? KT : KS;

    if (w >= 4) {
        // ---------------- PRODUCER ----------------
        const int pw = w - 4;
        const int sg = pw * 4 + grp;    // sample within block (0..15)
        float wih[10];
        #pragma unroll
        for (int d0 = 0; d0 < 10; ++d0) wih[d0] = W_ih[rw*10 + d0] * mneg;
        const float bsum = (b_ih[rw] + b_hh[rw]) * mneg;

        // staging offsets: element p = [t][s][d] within a chunk
        uint32_t voff[NLD];
        #pragma unroll
        for (int kk = 0; kk < NLD; ++kk) {
            int p   = (pw*NLD + kk)*64 + lane;
            int t   = p / 160;          // D_IN*SMP_BLK = 160
            int rem = p - t*160;
            int s   = rem / 10;
            int d0  = rem - s*10;
            voff[kk] = (samp0 + (uint32_t)s) * (uint32_t)(T_LEN*D_IN*4)
                     + (uint32_t)(t*40 + d0*4);
        }
        const char* Xc = (const char*)X;

        // xproj of one chunk from xbuf[bb] -> abuf[bb]
        auto produce = [&](int bb) {
            #pragma unroll 4
            for (int t = 0; t < CSTEP; ++t) {
                const float2* xp =
                    (const float2*)&xbuf[bb][(t*SMP_BLK + sg)*10];
                float2 x0 = xp[0], x1 = xp[1], x2 = xp[2],
                       x3 = xp[3], x4 = xp[4];
                float acc = bsum;
                acc = fmaf(wih[0], x0.x, acc); acc = fmaf(wih[1], x0.y, acc);
                acc = fmaf(wih[2], x1.x, acc); acc = fmaf(wih[3], x1.y, acc);
                acc = fmaf(wih[4], x2.x, acc); acc = fmaf(wih[5], x2.y, acc);
                acc = fmaf(wih[6], x3.x, acc); acc = fmaf(wih[7], x3.y, acc);
                acc = fmaf(wih[8], x4.x, acc); acc = fmaf(wih[9], x4.y, acc);
                abuf[bb][(t*SMP_BLK + sg)*16 + lr] = acc;
            }
        };

        // prologue: stage X(0)
        #pragma unroll
        for (int kk = 0; kk < NLD; ++kk)
            GLD4(Xc + voff[kk], &xbuf[0][(pw*NLD+kk)*64]);
        __syncthreads();                               // (1) X0 ready
        // stage X(1) (flies during compute), compute xacc(0)
        #pragma unroll
        for (int kk = 0; kk < NLD; ++kk)
            GLD4(Xc + (voff[kk] + CH_BYTES), &xbuf[1][(pw*NLD+kk)*64]);
        produce(0);
        __syncthreads();                               // (2) A0 + X1 ready

        for (int k = 0; k < NCH; ++k) {
            if (k + 1 < NCH) {
                if (k + 2 < NCH) {
                    const uint32_t add = (uint32_t)(k+2) * CH_BYTES;
                    #pragma unroll
                    for (int kk = 0; kk < NLD; ++kk)
                        GLD4(Xc + (voff[kk] + add),
                             &xbuf[k&1][(pw*NLD+kk)*64]);
                }
                produce((k+1)&1);
            }
            __syncthreads();
        }
    } else {
        // ---------------- CONSUMER ----------------
        __builtin_amdgcn_s_setprio(1);  // favor the serial-chain wave
        const int sg = w * 4 + grp;     // sample within block (0..15)
        //   tau=0 (i): a = KT*sigmoid   tau=1 (f): a = sigmoid
        //   tau=2 (g): a = tanh         tau=3 (o): a = 2*sigmoid
        const float k1 = (tau == 0) ? KT : ((tau == 1) ? 1.0f : 2.0f);
        const float k0 = (tau == 2) ? -1.0f : 0.0f;
        // rotated W_hh columns to match row_ror data placement
        const float whhA = W_hh[rw*4 +  u        ] * mneg;
        const float whhB = W_hh[rw*4 + ((u+3)&3)] * mneg;
        const float whhC = W_hh[rw*4 + ((u+2)&3)] * mneg;
        const float whhD = W_hh[rw*4 + ((u+1)&3)] * mneg;

        __syncthreads();                               // (1)
        __syncthreads();                               // (2)

        float cs = 0.f, hown = 0.f;
        for (int k = 0; k < NCH; ++k) {
            const float* ab = &abuf[k&1][sg*16 + lr];  // step stride 256 floats
            // preload the whole chunk into registers: one wait, then a
            // pure-register 32-step serial loop (no LDS on the chain).
            float xr[CSTEP];
            #pragma unroll
            for (int t = 0; t < CSTEP; ++t) xr[t] = ab[t*256];
            #pragma unroll
            for (int t = 0; t < CSTEP; ++t) {
                // ---- serial chain for step t ----
                float hB = dppf<0x124>(hown);   // h[(u-1)&3]
                float hC = dppf<0x128>(hown);   // h[(u-2)&3]
                float hD = dppf<0x12C>(hown);   // h[(u+1)&3]
                float u1 = fmaf(whhA, hown, xr[t]);
                float acc = fmaf(whhB, hB, u1) + fmaf(whhD, hD, whhC * hC);
                float e  = fast_exp2(acc);
                float a  = fmaf(k1, __builtin_amdgcn_rcpf(1.0f + e), k0);
                float gi = dppf<0x00>(a);       // KT*sigmoid(i)
                float gf = dppf<0x55>(a);       // sigmoid(f)
                float gg = dppf<0xAA>(a);       // tanh(g)
                float go = dppf<0xFF>(a);       // 2*sigmoid(o)
                float mgo = -0.5f * go;         // off-chain
                cs = fmaf(gf, cs, gi * gg);     // cs = KT * c
                float e2 = fast_exp2(cs);
                float r2 = __builtin_amdgcn_rcpf(1.0f + e2);
                hown = fmaf(go, r2, mgo);       // = sigmoid(o)*tanh(c)
            }
            __syncthreads();
        }
        if (tau == 0) hT[(samp0 + sg)*4 + u] = hown;
    }
}

// Head: logits = hT @ W_out^T + b_out, then softmax. One thread per sample.
__global__ void head_kernel(const float* __restrict__ hT,
                            const float* __restrict__ W_out,
                            const float* __restrict__ b_out,
                            float* __restrict__ out)
{
    int b = blockIdx.x * blockDim.x + threadIdx.x;
    if (b >= B_TOT) return;
    float4 h = ((const float4*)hT)[b];
    float lg[OUT_N];
    float m = -1e30f;
    #pragma unroll
    for (int o = 0; o < OUT_N; ++o) {
        float v = b_out[o];
        v = fmaf(W_out[o*4+0], h.x, v);
        v = fmaf(W_out[o*4+1], h.y, v);
        v = fmaf(W_out[o*4+2], h.z, v);
        v = fmaf(W_out[o*4+3], h.w, v);
        lg[o] = v;
        m = fmaxf(m, v);
    }
    float s = 0.f;
    #pragma unroll
    for (int o = 0; o < OUT_N; ++o) {
        float e = fast_exp2((lg[o] - m) * 1.4426950408889634f);
        lg[o] = e;
        s += e;
    }
    float rs = 1.0f / s;
    #pragma unroll
    for (int o = 0; o < OUT_N; ++o) out[(size_t)b*OUT_N + o] = lg[o] * rs;
}

extern "C" void kernel_launch(void* const* d_in, const int* in_sizes, int n_in,
                              void* d_out, int out_size, void* d_ws, size_t ws_size,
                              hipStream_t stream)
{
    const float* X     = (const float*)d_in[0];
    const float* W_ih  = (const float*)d_in[1];
    const float* W_hh  = (const float*)d_in[2];
    const float* b_ih  = (const float*)d_in[3];
    const float* b_hh  = (const float*)d_in[4];
    const float* W_out = (const float*)d_in[5];
    const float* b_out = (const float*)d_in[6];
    float* out = (float*)d_out;
    float* hTs = (float*)d_ws;   // 4096*4 floats = 64 KB scratch

    lstm_scan_kernel<<<B_TOT/SMP_BLK, 512, 0, stream>>>(X, W_ih, W_hh, b_ih, b_hh, hTs);
    head_kernel<<<B_TOT/256, 256, 0, stream>>>(hTs, W_out, b_out, out);
}